// Round 2
// baseline (304.579 us; speedup 1.0000x reference)
//
#include <hip/hip_runtime.h>
#include <hip/hip_fp16.h>

// ---------------- types ----------------
typedef _Float16 half8_t __attribute__((ext_vector_type(8)));
typedef _Float16 half4_t __attribute__((ext_vector_type(4)));
typedef float    f32x4   __attribute__((ext_vector_type(4)));

#define LOG2E 1.4426950408889634f
// SCALE = 1/sqrt(32); fold log2(e) so we can use exp2
#define KSCALE (0.17677669529663687f * LOG2E)

// ---------------------------------------------------------------------------
// prep_misc: x->f16, Wqkv^T->f16, Wout^T->f16, coords MLP-layer1 precompute
//   APre[row][k]  k<16 : coords.pos_w1 + pos_b1      (query side, direct)
//                 k>=16: coords.sym_w1 + sym_b1      (query side, sym)
//   BPre[row][k]  k<16 : coords.pos_w1               (key side, direct)
//                 k>=16: (coords*reflect).sym_w1     (key side, sym)
// ---------------------------------------------------------------------------
__global__ __launch_bounds__(256) void prep_misc(
    const float* __restrict__ x, const float* __restrict__ Wqkv,
    const float* __restrict__ Wout, const float* __restrict__ coords,
    const float* __restrict__ pw1, const float* __restrict__ pb1,
    const float* __restrict__ sw1, const float* __restrict__ sb1,
    _Float16* __restrict__ xf16, _Float16* __restrict__ WqkvT,
    _Float16* __restrict__ WoutT, _Float16* __restrict__ APre,
    _Float16* __restrict__ BPre)
{
  const int bi = blockIdx.x, tid = threadIdx.x;
  if (bi < 1024) {                       // x cast: 1,048,576 floats
    const int idx = bi * 256 + tid;
    f32x4 v = *reinterpret_cast<const f32x4*>(x + idx * 4);
    half4_t h;
    h[0] = (_Float16)v[0]; h[1] = (_Float16)v[1];
    h[2] = (_Float16)v[2]; h[3] = (_Float16)v[3];
    *reinterpret_cast<half4_t*>(xf16 + idx * 4) = h;
  } else if (bi < 1792) {                // Wqkv^T : [768][256]
    const int o = bi - 1024, k = tid;
    WqkvT[o * 256 + k] = (_Float16)Wqkv[k * 768 + o];
  } else if (bi < 2048) {                // Wout^T : [256][256]
    const int o = bi - 1792, k = tid;
    WoutT[o * 256 + k] = (_Float16)Wout[k * 256 + o];
  } else {                               // coords precompute: 4096 rows
    const int row = (bi - 2048) * 256 + tid;
    const float c0 = coords[row * 3 + 0];
    const float c1 = coords[row * 3 + 1];
    const float c2 = coords[row * 3 + 2];
#pragma unroll
    for (int k = 0; k < 16; ++k) {
      float a = c0 * pw1[k] + c1 * pw1[16 + k] + c2 * pw1[32 + k];
      APre[row * 32 + k] = (_Float16)(a + pb1[k]);
      BPre[row * 32 + k] = (_Float16)a;
      float s  =  c0 * sw1[k] + c1 * sw1[16 + k] + c2 * sw1[32 + k];
      float sb = -c0 * sw1[k] + c1 * sw1[16 + k] + c2 * sw1[32 + k];
      APre[row * 32 + 16 + k] = (_Float16)(s + sb1[k]);
      BPre[row * 32 + 16 + k] = (_Float16)sb;
    }
  }
}

// ---------------------------------------------------------------------------
// qkv_gemm: [4096x768] = xf16[4096x256] @ Wqkv; one 16x16 tile per wave.
// Scatter epilogue: Qh/Kh = [B][H][N][32] f16, Vt = [B][H][32][N] f16.
// ---------------------------------------------------------------------------
__global__ __launch_bounds__(256) void qkv_gemm(
    const _Float16* __restrict__ xf16, const _Float16* __restrict__ WqkvT,
    _Float16* __restrict__ Qh, _Float16* __restrict__ Kh,
    _Float16* __restrict__ Vt)
{
  const int wg = blockIdx.x * 4 + (threadIdx.x >> 6);
  const int ti = wg / 48, to = wg % 48;
  const int i0 = ti * 16, o0 = to * 16;
  const int lane = threadIdx.x & 63, q = lane >> 4, c = lane & 15;
  f32x4 acc = {0.f, 0.f, 0.f, 0.f};
  const _Float16* arow = xf16 + (i0 + c) * 256;
  const _Float16* brow = WqkvT + (o0 + c) * 256;
#pragma unroll
  for (int k0 = 0; k0 < 256; k0 += 32) {
    half8_t af = *reinterpret_cast<const half8_t*>(arow + k0 + q * 8);
    half8_t bf = *reinterpret_cast<const half8_t*>(brow + k0 + q * 8);
    acc = __builtin_amdgcn_mfma_f32_16x16x32_f16(af, bf, acc, 0, 0, 0);
  }
  const int o = o0 + c;
  const int which = o >> 8, h = (o >> 5) & 7, d = o & 31;
#pragma unroll
  for (int r = 0; r < 4; ++r) {
    const int i = i0 + q * 4 + r;
    const int b = i >> 11, n = i & 2047;
    _Float16 v = (_Float16)acc[r];
    if (which == 0)      Qh[((b * 8 + h) * 2048 + n) * 32 + d] = v;
    else if (which == 1) Kh[((b * 8 + h) * 2048 + n) * 32 + d] = v;
    else                 Vt[((b * 8 + h) * 32 + d) * 2048 + n] = v;
  }
}

// ---------------------------------------------------------------------------
// flash: one block per (b, 16-row q-tile); 8 waves, wave w = head w.
// j-tile = 32. Bias MLP hidden: scalar f32 per pair (one pair/thread),
// 16->8 layer (both MLPs, K concatenated to 32) via one MFMA per j-column.
// Three __syncthreads per tile: hid-ready, biasF-ready, pbuf-ready.
// ---------------------------------------------------------------------------
__global__ __launch_bounds__(512) void flash(
    const _Float16* __restrict__ Qh, const _Float16* __restrict__ Kh,
    const _Float16* __restrict__ Vt, const _Float16* __restrict__ APre,
    const _Float16* __restrict__ BPre, const float* __restrict__ pw2,
    const float* __restrict__ sw2, _Float16* __restrict__ attnF16)
{
  __shared__ __align__(16) unsigned char smem[65536];
  _Float16* hid  = reinterpret_cast<_Float16*>(smem);           // 512 pairs x 40 halves (80B stride)
  float*   biasF = reinterpret_cast<float*>(smem + 40960);      // [8 heads][32 j][16 i]
  _Float16* pbuf = reinterpret_cast<_Float16*>(smem + 57344);   // [8 waves][16 i][32 j]

  const int b  = blockIdx.x >> 7;
  const int i0 = (blockIdx.x & 127) << 4;
  const int tid = threadIdx.x;
  const int w = tid >> 6;              // wave id == head
  const int lane = tid & 63;
  const int q = lane >> 4, c = lane & 15;
  const int pi = tid & 15;             // pair i-local
  const int pj = tid >> 4;             // pair j-local (0..31)

  // Q fragment (A-operand): row = i0+c, k = d
  half8_t qf = *reinterpret_cast<const half8_t*>(
      Qh + ((b * 8 + w) * 2048 + i0 + c) * 32 + q * 8);

  // stacked W2 B-fragment: B[k][n], k<16 -> pos_w2, k>=16 -> sym_w2; *LOG2E
  half8_t w2f;
#pragma unroll
  for (int jj = 0; jj < 8; ++jj) {
    const int k = q * 8 + jj;
    float val = 0.f;
    if (c < 8) val = (k < 16 ? pw2[k * 8 + c] : sw2[(k - 16) * 8 + c]) * LOG2E;
    w2f[jj] = (_Float16)val;
  }

  // APre for this thread's query row (j-invariant), 32 halves
  half8_t ap[4];
  {
    const half8_t* p = reinterpret_cast<const half8_t*>(APre + (b * 2048 + i0 + pi) * 32);
    ap[0] = p[0]; ap[1] = p[1]; ap[2] = p[2]; ap[3] = p[3];
  }

  float m[4], l[4];
  f32x4 O0 = {0.f, 0.f, 0.f, 0.f}, O1 = {0.f, 0.f, 0.f, 0.f};
#pragma unroll
  for (int r = 0; r < 4; ++r) { m[r] = -INFINITY; l[r] = 0.f; }

  const f32x4 z4 = {0.f, 0.f, 0.f, 0.f};

  for (int j0 = 0; j0 < 2048; j0 += 32) {
    // ---- hidden layer for pair (i0+pi, j0+pj), both MLPs, scalar f32 ----
    {
      const half8_t* bpp = reinterpret_cast<const half8_t*>(BPre + (b * 2048 + j0 + pj) * 32);
#pragma unroll
      for (int part = 0; part < 4; ++part) {
        half8_t bp = bpp[part];
        half8_t hv;
#pragma unroll
        for (int e = 0; e < 8; ++e) {
          float d = (float)ap[part][e] - (float)bp[e];
          hv[e] = (_Float16)fmaxf(d, 0.f);
        }
        *reinterpret_cast<half8_t*>(hid + tid * 40 + part * 8) = hv;
      }
    }
    __syncthreads();   // S1: hid ready

    // ---- global fragments for this head ----
    const _Float16* kbase = Kh + ((b * 8 + w) * 2048 + j0) * 32;
    half8_t kf0 = *reinterpret_cast<const half8_t*>(kbase + c * 32 + q * 8);
    half8_t kf1 = *reinterpret_cast<const half8_t*>(kbase + (16 + c) * 32 + q * 8);
    const _Float16* vbase = Vt + (b * 8 + w) * 32 * 2048 + j0;
    half8_t vf0 = *reinterpret_cast<const half8_t*>(vbase + c * 2048 + q * 8);
    half8_t vf1 = *reinterpret_cast<const half8_t*>(vbase + (16 + c) * 2048 + q * 8);

    // ---- scores: S = Q K^T (two 16x16 tiles) ----
    f32x4 s0 = __builtin_amdgcn_mfma_f32_16x16x32_f16(qf, kf0, z4, 0, 0, 0);
    f32x4 s1 = __builtin_amdgcn_mfma_f32_16x16x32_f16(qf, kf1, z4, 0, 0, 0);

    // ---- bias second layer via MFMA: 4 j-columns per wave ----
#pragma unroll
    for (int mt = 0; mt < 4; ++mt) {
      const int jl = w * 4 + mt;
      half8_t ha = *reinterpret_cast<const half8_t*>(hid + (jl * 16 + c) * 40 + q * 8);
      f32x4 bc = __builtin_amdgcn_mfma_f32_16x16x32_f16(ha, w2f, z4, 0, 0, 0);
      if (c < 8)   // C cols 0..7 = heads
        *reinterpret_cast<f32x4*>(biasF + c * 512 + jl * 16 + q * 4) = bc;
    }
    __syncthreads();   // S2: biasF ready

    const f32x4 bb0 = *reinterpret_cast<const f32x4*>(biasF + w * 512 + c * 16 + q * 4);
    const f32x4 bb1 = *reinterpret_cast<const f32x4*>(biasF + w * 512 + (c + 16) * 16 + q * 4);

    // ---- online softmax (rows spread across the 16 lanes of a quad) ----
#pragma unroll
    for (int r = 0; r < 4; ++r) {
      float sv0 = s0[r] * KSCALE + bb0[r];
      float sv1 = s1[r] * KSCALE + bb1[r];
      float mr = fmaxf(sv0, sv1);
      mr = fmaxf(mr, __shfl_xor(mr, 1, 16));
      mr = fmaxf(mr, __shfl_xor(mr, 2, 16));
      mr = fmaxf(mr, __shfl_xor(mr, 4, 16));
      mr = fmaxf(mr, __shfl_xor(mr, 8, 16));
      const float mnew = fmaxf(m[r], mr);
      const float alpha = exp2f(m[r] - mnew);
      const float p0 = exp2f(sv0 - mnew);
      const float p1 = exp2f(sv1 - mnew);
      float rs = p0 + p1;
      rs += __shfl_xor(rs, 1, 16);
      rs += __shfl_xor(rs, 2, 16);
      rs += __shfl_xor(rs, 4, 16);
      rs += __shfl_xor(rs, 8, 16);
      l[r] = l[r] * alpha + rs;
      m[r] = mnew;
      O0[r] *= alpha; O1[r] *= alpha;
      pbuf[(w << 9) + (q * 4 + r) * 32 + c]      = (_Float16)p0;
      pbuf[(w << 9) + (q * 4 + r) * 32 + 16 + c] = (_Float16)p1;
    }
    __syncthreads();   // S3: pbuf ready (hard ordering for the P round-trip)
    half8_t pf = *reinterpret_cast<const half8_t*>(pbuf + (w << 9) + c * 32 + q * 8);
    O0 = __builtin_amdgcn_mfma_f32_16x16x32_f16(pf, vf0, O0, 0, 0, 0);
    O1 = __builtin_amdgcn_mfma_f32_16x16x32_f16(pf, vf1, O1, 0, 0, 0);
  }

#pragma unroll
  for (int r = 0; r < 4; ++r) {
    const float inv = 1.f / l[r];
    const int n = i0 + q * 4 + r;
    attnF16[(b * 2048 + n) * 256 + w * 32 + c]      = (_Float16)(O0[r] * inv);
    attnF16[(b * 2048 + n) * 256 + w * 32 + 16 + c] = (_Float16)(O1[r] * inv);
  }
}

// ---------------------------------------------------------------------------
// proj: out = attn @ W_out + b_out  (f32 output)
// ---------------------------------------------------------------------------
__global__ __launch_bounds__(256) void proj(
    const _Float16* __restrict__ attnF16, const _Float16* __restrict__ WoutT,
    const float* __restrict__ bout, float* __restrict__ out)
{
  const int wg = blockIdx.x * 4 + (threadIdx.x >> 6);
  const int ti = wg >> 4, to = wg & 15;
  const int i0 = ti * 16, o0 = to * 16;
  const int lane = threadIdx.x & 63, q = lane >> 4, c = lane & 15;
  f32x4 acc = {0.f, 0.f, 0.f, 0.f};
  const _Float16* arow = attnF16 + (i0 + c) * 256;
  const _Float16* brow = WoutT + (o0 + c) * 256;
#pragma unroll
  for (int k0 = 0; k0 < 256; k0 += 32) {
    half8_t af = *reinterpret_cast<const half8_t*>(arow + k0 + q * 8);
    half8_t bf = *reinterpret_cast<const half8_t*>(brow + k0 + q * 8);
    acc = __builtin_amdgcn_mfma_f32_16x16x32_f16(af, bf, acc, 0, 0, 0);
  }
  const float bo = bout[o0 + c];
#pragma unroll
  for (int r = 0; r < 4; ++r)
    out[(i0 + q * 4 + r) * 256 + o0 + c] = acc[r] + bo;
}

// ---------------------------------------------------------------------------
extern "C" void kernel_launch(void* const* d_in, const int* in_sizes, int n_in,
                              void* d_out, int out_size, void* d_ws, size_t ws_size,
                              hipStream_t stream)
{
  const float* x      = (const float*)d_in[0];
  const float* coords = (const float*)d_in[1];
  const float* Wqkv   = (const float*)d_in[2];
  const float* Wout   = (const float*)d_in[3];
  const float* bout   = (const float*)d_in[4];
  const float* pw1    = (const float*)d_in[5];
  const float* pb1    = (const float*)d_in[6];
  const float* pw2    = (const float*)d_in[7];
  const float* sw1    = (const float*)d_in[9];
  const float* sb1    = (const float*)d_in[10];
  const float* sw2    = (const float*)d_in[11];
  float* out = (float*)d_out;

  char* ws = (char*)d_ws;
  _Float16* Qh      = (_Float16*)(ws + 0);        // 2 MB
  _Float16* Kh      = (_Float16*)(ws + 2097152);  // 2 MB
  _Float16* Vt      = (_Float16*)(ws + 4194304);  // 2 MB
  _Float16* xf16    = (_Float16*)(ws + 6291456);  // 2 MB (dead after qkv_gemm)
  _Float16* attnF16 = (_Float16*)(ws + 6291456);  // overlaid on xf16
  _Float16* WqkvT   = (_Float16*)(ws + 8388608);  // 384 KB
  _Float16* WoutT   = (_Float16*)(ws + 8781824);  // 128 KB
  _Float16* APre    = (_Float16*)(ws + 8912896);  // 256 KB
  _Float16* BPre    = (_Float16*)(ws + 9175040);  // 256 KB -> total 9,437,184 B

  prep_misc<<<2064, 256, 0, stream>>>(x, Wqkv, Wout, coords, pw1, pb1, sw1, sb1,
                                      xf16, WqkvT, WoutT, APre, BPre);
  qkv_gemm<<<3072, 256, 0, stream>>>(xf16, WqkvT, Qh, Kh, Vt);
  flash<<<256, 512, 0, stream>>>(Qh, Kh, Vt, APre, BPre, pw2, sw2, attnF16);
  proj<<<1024, 256, 0, stream>>>(attnF16, WoutT, bout, out);
}

// Round 3
// 229.183 us; speedup vs baseline: 1.3290x; 1.3290x over previous
//
#include <hip/hip_runtime.h>
#include <hip/hip_fp16.h>

// ---------------- types ----------------
typedef _Float16 half8_t __attribute__((ext_vector_type(8)));
typedef _Float16 half4_t __attribute__((ext_vector_type(4)));
typedef _Float16 h2      __attribute__((ext_vector_type(2)));
typedef float    f32x4   __attribute__((ext_vector_type(4)));

#define LOG2E 1.4426950408889634f
// SCALE = 1/sqrt(32); fold log2(e) so we can use exp2
#define KSCALE (0.17677669529663687f * LOG2E)

#if __has_builtin(__builtin_amdgcn_exp2f)
#define EXP2F(x) __builtin_amdgcn_exp2f(x)
#else
#define EXP2F(x) exp2f(x)
#endif

// ---------------------------------------------------------------------------
// prep_misc: x->f16, Wqkv^T->f16, Wout^T->f16, coords MLP-layer1 precompute
// ---------------------------------------------------------------------------
__global__ __launch_bounds__(256) void prep_misc(
    const float* __restrict__ x, const float* __restrict__ Wqkv,
    const float* __restrict__ Wout, const float* __restrict__ coords,
    const float* __restrict__ pw1, const float* __restrict__ pb1,
    const float* __restrict__ sw1, const float* __restrict__ sb1,
    _Float16* __restrict__ xf16, _Float16* __restrict__ WqkvT,
    _Float16* __restrict__ WoutT, _Float16* __restrict__ APre,
    _Float16* __restrict__ BPre)
{
  const int bi = blockIdx.x, tid = threadIdx.x;
  if (bi < 1024) {                       // x cast: 1,048,576 floats
    const int idx = bi * 256 + tid;
    f32x4 v = *reinterpret_cast<const f32x4*>(x + idx * 4);
    half4_t h;
    h[0] = (_Float16)v[0]; h[1] = (_Float16)v[1];
    h[2] = (_Float16)v[2]; h[3] = (_Float16)v[3];
    *reinterpret_cast<half4_t*>(xf16 + idx * 4) = h;
  } else if (bi < 1792) {                // Wqkv^T : [768][256]
    const int o = bi - 1024, k = tid;
    WqkvT[o * 256 + k] = (_Float16)Wqkv[k * 768 + o];
  } else if (bi < 2048) {                // Wout^T : [256][256]
    const int o = bi - 1792, k = tid;
    WoutT[o * 256 + k] = (_Float16)Wout[k * 256 + o];
  } else {                               // coords precompute: 4096 rows
    const int row = (bi - 2048) * 256 + tid;
    const float c0 = coords[row * 3 + 0];
    const float c1 = coords[row * 3 + 1];
    const float c2 = coords[row * 3 + 2];
#pragma unroll
    for (int k = 0; k < 16; ++k) {
      float a = c0 * pw1[k] + c1 * pw1[16 + k] + c2 * pw1[32 + k];
      APre[row * 32 + k] = (_Float16)(a + pb1[k]);
      BPre[row * 32 + k] = (_Float16)a;
      float s  =  c0 * sw1[k] + c1 * sw1[16 + k] + c2 * sw1[32 + k];
      float sb = -c0 * sw1[k] + c1 * sw1[16 + k] + c2 * sw1[32 + k];
      APre[row * 32 + 16 + k] = (_Float16)(s + sb1[k]);
      BPre[row * 32 + 16 + k] = (_Float16)sb;
    }
  }
}

// ---------------------------------------------------------------------------
// qkv_gemm: [4096x768] = xf16[4096x256] @ Wqkv; one 16x16 tile per wave.
// ---------------------------------------------------------------------------
__global__ __launch_bounds__(256) void qkv_gemm(
    const _Float16* __restrict__ xf16, const _Float16* __restrict__ WqkvT,
    _Float16* __restrict__ Qh, _Float16* __restrict__ Kh,
    _Float16* __restrict__ Vt)
{
  const int wg = blockIdx.x * 4 + (threadIdx.x >> 6);
  const int ti = wg / 48, to = wg % 48;
  const int i0 = ti * 16, o0 = to * 16;
  const int lane = threadIdx.x & 63, q = lane >> 4, c = lane & 15;
  f32x4 acc = {0.f, 0.f, 0.f, 0.f};
  const _Float16* arow = xf16 + (i0 + c) * 256;
  const _Float16* brow = WqkvT + (o0 + c) * 256;
#pragma unroll
  for (int k0 = 0; k0 < 256; k0 += 32) {
    half8_t af = *reinterpret_cast<const half8_t*>(arow + k0 + q * 8);
    half8_t bf = *reinterpret_cast<const half8_t*>(brow + k0 + q * 8);
    acc = __builtin_amdgcn_mfma_f32_16x16x32_f16(af, bf, acc, 0, 0, 0);
  }
  const int o = o0 + c;
  const int which = o >> 8, h = (o >> 5) & 7, d = o & 31;
#pragma unroll
  for (int r = 0; r < 4; ++r) {
    const int i = i0 + q * 4 + r;
    const int b = i >> 11, n = i & 2047;
    _Float16 v = (_Float16)acc[r];
    if (which == 0)      Qh[((b * 8 + h) * 2048 + n) * 32 + d] = v;
    else if (which == 1) Kh[((b * 8 + h) * 2048 + n) * 32 + d] = v;
    else                 Vt[((b * 8 + h) * 32 + d) * 2048 + n] = v;
  }
}

// ---------------------------------------------------------------------------
// flash: grid = [b:2][chunk:4][itile:128]; block = 512 thr, wave w = head w.
// Each block handles 16 q-rows x 512 j (its chunk) -> partial O with (m,l).
// Per j-tile(32): reg-resident hidden frags -> bias MFMA -> biasF (dbuf, ONE
// barrier) -> scores MFMA -> online softmax (packed-f16 max shuffles, lane-
// local l) -> P via wave-private pbuf (fence only) -> PV MFMA.
// ---------------------------------------------------------------------------
__global__ __launch_bounds__(512, 6) void flash(
    const _Float16* __restrict__ Qh, const _Float16* __restrict__ Kh,
    const _Float16* __restrict__ Vt, const _Float16* __restrict__ APre,
    const _Float16* __restrict__ BPre, const float* __restrict__ pw2,
    const float* __restrict__ sw2, _Float16* __restrict__ Opart,
    float* __restrict__ Mpart)
{
  __shared__ __align__(16) unsigned char smem[43264];
  float*    biasF = reinterpret_cast<float*>(smem);            // [2][8h][516] f32
  _Float16* pbuf  = reinterpret_cast<_Float16*>(smem + 33024); // [8w][16i x 40] f16

  const int blk = blockIdx.x;
  const int b     = blk >> 9;
  const int chunk = (blk >> 7) & 3;
  const int i0    = (blk & 127) << 4;
  const int tid = threadIdx.x;
  const int w = tid >> 6, lane = tid & 63;
  const int q = lane >> 4, c = lane & 15;

  // Q fragment (A-operand): row = i0+c, k = d
  half8_t qf = *reinterpret_cast<const half8_t*>(
      Qh + ((b * 8 + w) * 2048 + i0 + c) * 32 + q * 8);
  // APre fragment for bias-MFMA A side (i = c), j-invariant
  half8_t apf = *reinterpret_cast<const half8_t*>(
      APre + (b * 2048 + i0 + c) * 32 + q * 8);

  // stacked W2 B-fragment: B[k][n], k<16 -> pos_w2, k>=16 -> sym_w2; *LOG2E
  half8_t w2f;
#pragma unroll
  for (int jj = 0; jj < 8; ++jj) {
    const int k = q * 8 + jj;
    float val = 0.f;
    if (c < 8) val = (k < 16 ? pw2[k * 8 + c] : sw2[(k - 16) * 8 + c]) * LOG2E;
    w2f[jj] = (_Float16)val;
  }

  float m[4], lp[4];
  f32x4 O0 = {0.f, 0.f, 0.f, 0.f}, O1 = {0.f, 0.f, 0.f, 0.f};
#pragma unroll
  for (int r = 0; r < 4; ++r) { m[r] = -INFINITY; lp[r] = 0.f; }

  const f32x4 z4 = {0.f, 0.f, 0.f, 0.f};
  half8_t hzero8 = {};

  const int jbase = chunk * 512;
  for (int jt = 0; jt < 16; ++jt) {
    const int j0 = jbase + jt * 32;
    float* bW = biasF + (jt & 1) * 4128;

    // ---- bias: reg-resident hidden frag + MFMA, 4 j-columns per wave ----
#pragma unroll
    for (int mt = 0; mt < 4; ++mt) {
      const int jl = w * 4 + mt;
      half8_t bpf = *reinterpret_cast<const half8_t*>(
          BPre + (b * 2048 + j0 + jl) * 32 + q * 8);
      half8_t hv = __builtin_elementwise_max(apf - bpf, hzero8);
      f32x4 bc = __builtin_amdgcn_mfma_f32_16x16x32_f16(hv, w2f, z4, 0, 0, 0);
      if (c < 8)   // C cols 0..7 = heads; [h][j][i] with head-stride 516
        *reinterpret_cast<f32x4*>(bW + c * 516 + jl * 16 + q * 4) = bc;
    }

    // ---- K/V fragments; scores (independent of biasF) ----
    const _Float16* kbase = Kh + ((b * 8 + w) * 2048 + j0) * 32;
    half8_t kf0 = *reinterpret_cast<const half8_t*>(kbase + (2 * c) * 32 + q * 8);
    half8_t kf1 = *reinterpret_cast<const half8_t*>(kbase + (2 * c + 1) * 32 + q * 8);
    const _Float16* vbase = Vt + (b * 8 + w) * 65536 + j0;
    half8_t vf0 = *reinterpret_cast<const half8_t*>(vbase + c * 2048 + q * 8);
    half8_t vf1 = *reinterpret_cast<const half8_t*>(vbase + (16 + c) * 2048 + q * 8);
    f32x4 s0 = __builtin_amdgcn_mfma_f32_16x16x32_f16(qf, kf0, z4, 0, 0, 0);
    f32x4 s1 = __builtin_amdgcn_mfma_f32_16x16x32_f16(qf, kf1, z4, 0, 0, 0);

    __syncthreads();   // biasF[jt&1] ready (sole barrier this iteration)

    const float* bR = biasF + (jt & 1) * 4128 + w * 516;
    f32x4 bb0 = *reinterpret_cast<const f32x4*>(bR + (2 * c) * 16 + q * 4);
    f32x4 bb1 = *reinterpret_cast<const f32x4*>(bR + (2 * c + 1) * 16 + q * 4);

    // ---- online softmax; rows r in C-layout (row = q*4+r), j = 2c,2c+1 ----
    float sv0[4], sv1[4];
    h2 pk01, pk23;
    {
      float mr[4];
#pragma unroll
      for (int r = 0; r < 4; ++r) {
        sv0[r] = s0[r] * KSCALE + bb0[r];
        sv1[r] = s1[r] * KSCALE + bb1[r];
        mr[r] = fmaxf(sv0[r], sv1[r]);
      }
      pk01[0] = (_Float16)mr[0]; pk01[1] = (_Float16)mr[1];
      pk23[0] = (_Float16)mr[2]; pk23[1] = (_Float16)mr[3];
#pragma unroll
      for (int s = 1; s < 16; s <<= 1) {
        int u01 = __shfl_xor(__builtin_bit_cast(int, pk01), s, 16);
        pk01 = __builtin_elementwise_max(pk01, __builtin_bit_cast(h2, u01));
        int u23 = __shfl_xor(__builtin_bit_cast(int, pk23), s, 16);
        pk23 = __builtin_elementwise_max(pk23, __builtin_bit_cast(h2, u23));
      }
    }
    float mred[4] = {(float)pk01[0], (float)pk01[1], (float)pk23[0], (float)pk23[1]};
#pragma unroll
    for (int r = 0; r < 4; ++r) {
      const float mnew = fmaxf(m[r], mred[r]);
      const float alpha = EXP2F(m[r] - mnew);
      const float p0 = EXP2F(sv0[r] - mnew);
      const float p1 = EXP2F(sv1[r] - mnew);
      lp[r] = lp[r] * alpha + (p0 + p1);   // lane-local partial; reduce at end
      m[r] = mnew;
      O0[r] *= alpha; O1[r] *= alpha;
      h2 pp; pp[0] = (_Float16)p0; pp[1] = (_Float16)p1;
      *reinterpret_cast<h2*>(pbuf + w * 640 + (q * 4 + r) * 40 + 2 * c) = pp;
    }
    __threadfence_block();   // wave-private pbuf: order write->read, no barrier
    half8_t pf = *reinterpret_cast<const half8_t*>(pbuf + w * 640 + c * 40 + q * 8);
    O0 = __builtin_amdgcn_mfma_f32_16x16x32_f16(pf, vf0, O0, 0, 0, 0);
    O1 = __builtin_amdgcn_mfma_f32_16x16x32_f16(pf, vf1, O1, 0, 0, 0);
  }

  // ---- finalize: reduce l across the 16 lanes of each row, store partials ----
#pragma unroll
  for (int r = 0; r < 4; ++r) {
    float s = lp[r];
#pragma unroll
    for (int t = 1; t < 16; t <<= 1) s += __shfl_xor(s, t, 16);
    const float inv = 1.f / s;
    const int n = i0 + q * 4 + r;
    const long base = (long)(((chunk * 2 + b) * 8 + w) * 2048 + n);
    Opart[base * 32 + c]      = (_Float16)(O0[r] * inv);
    Opart[base * 32 + 16 + c] = (_Float16)(O1[r] * inv);
    if (c == 0) Mpart[base] = m[r] + __log2f(s);
  }
}

// ---------------------------------------------------------------------------
// combine: merge 4 j-chunk partials -> attnF16 [B*N][256]
// ---------------------------------------------------------------------------
__global__ __launch_bounds__(256) void combine(
    const _Float16* __restrict__ Opart, const float* __restrict__ Mpart,
    _Float16* __restrict__ attnF16)
{
  const int idx = blockIdx.x * 256 + threadIdx.x;   // 1,048,576
  const int d = idx & 31, h = (idx >> 5) & 7;
  const int rest = idx >> 8;
  const int n = rest & 2047, b = rest >> 11;
  float mv[4], M = -INFINITY;
#pragma unroll
  for (int ck = 0; ck < 4; ++ck) {
    mv[ck] = Mpart[((ck * 2 + b) * 8 + h) * 2048 + n];
    M = fmaxf(M, mv[ck]);
  }
  float num = 0.f, den = 0.f;
#pragma unroll
  for (int ck = 0; ck < 4; ++ck) {
    const float wgt = EXP2F(mv[ck] - M);
    num += wgt * (float)Opart[(long)(((ck * 2 + b) * 8 + h) * 2048 + n) * 32 + d];
    den += wgt;
  }
  attnF16[idx] = (_Float16)(num / den);
}

// ---------------------------------------------------------------------------
// proj: out = attn @ W_out + b_out  (f32 output)
// ---------------------------------------------------------------------------
__global__ __launch_bounds__(256) void proj(
    const _Float16* __restrict__ attnF16, const _Float16* __restrict__ WoutT,
    const float* __restrict__ bout, float* __restrict__ out)
{
  const int wg = blockIdx.x * 4 + (threadIdx.x >> 6);
  const int ti = wg >> 4, to = wg & 15;
  const int i0 = ti * 16, o0 = to * 16;
  const int lane = threadIdx.x & 63, q = lane >> 4, c = lane & 15;
  f32x4 acc = {0.f, 0.f, 0.f, 0.f};
  const _Float16* arow = attnF16 + (i0 + c) * 256;
  const _Float16* brow = WoutT + (o0 + c) * 256;
#pragma unroll
  for (int k0 = 0; k0 < 256; k0 += 32) {
    half8_t af = *reinterpret_cast<const half8_t*>(arow + k0 + q * 8);
    half8_t bf = *reinterpret_cast<const half8_t*>(brow + k0 + q * 8);
    acc = __builtin_amdgcn_mfma_f32_16x16x32_f16(af, bf, acc, 0, 0, 0);
  }
  const float bo = bout[o0 + c];
#pragma unroll
  for (int r = 0; r < 4; ++r)
    out[(i0 + q * 4 + r) * 256 + o0 + c] = acc[r] + bo;
}

// ---------------------------------------------------------------------------
extern "C" void kernel_launch(void* const* d_in, const int* in_sizes, int n_in,
                              void* d_out, int out_size, void* d_ws, size_t ws_size,
                              hipStream_t stream)
{
  const float* x      = (const float*)d_in[0];
  const float* coords = (const float*)d_in[1];
  const float* Wqkv   = (const float*)d_in[2];
  const float* Wout   = (const float*)d_in[3];
  const float* bout   = (const float*)d_in[4];
  const float* pw1    = (const float*)d_in[5];
  const float* pb1    = (const float*)d_in[6];
  const float* pw2    = (const float*)d_in[7];
  const float* sw1    = (const float*)d_in[9];
  const float* sb1    = (const float*)d_in[10];
  const float* sw2    = (const float*)d_in[11];
  float* out = (float*)d_out;

  char* ws = (char*)d_ws;
  _Float16* Qh      = (_Float16*)(ws + 0);         // 2 MB
  _Float16* Kh      = (_Float16*)(ws + 2097152);   // 2 MB
  _Float16* Vt      = (_Float16*)(ws + 4194304);   // 2 MB
  _Float16* xf16    = (_Float16*)(ws + 6291456);   // 2 MB (dead after qkv_gemm)
  _Float16* attnF16 = (_Float16*)(ws + 6291456);   // overlaid on xf16
  _Float16* WqkvT   = (_Float16*)(ws + 8388608);   // 384 KB
  _Float16* WoutT   = (_Float16*)(ws + 8781824);   // 128 KB
  _Float16* APre    = (_Float16*)(ws + 8912896);   // 256 KB
  _Float16* BPre    = (_Float16*)(ws + 9175040);   // 256 KB
  _Float16* Opart   = (_Float16*)(ws + 9437184);   // 8 MB  [4][2][8][2048][32]
  float*    Mpart   = (float*)   (ws + 17825792);  // 512 KB [4][2][8][2048]

  prep_misc<<<2064, 256, 0, stream>>>(x, Wqkv, Wout, coords, pw1, pb1, sw1, sb1,
                                      xf16, WqkvT, WoutT, APre, BPre);
  qkv_gemm<<<3072, 256, 0, stream>>>(xf16, WqkvT, Qh, Kh, Vt);
  flash<<<1024, 512, 0, stream>>>(Qh, Kh, Vt, APre, BPre, pw2, sw2, Opart, Mpart);
  combine<<<4096, 256, 0, stream>>>(Opart, Mpart, attnF16);
  proj<<<1024, 256, 0, stream>>>(attnF16, WoutT, bout, out);
}

// Round 4
// 217.041 us; speedup vs baseline: 1.4033x; 1.0559x over previous
//
#include <hip/hip_runtime.h>
#include <hip/hip_fp16.h>

// ---------------- types ----------------
typedef _Float16 half8_t __attribute__((ext_vector_type(8)));
typedef _Float16 half4_t __attribute__((ext_vector_type(4)));
typedef _Float16 h2      __attribute__((ext_vector_type(2)));
typedef float    f32x4   __attribute__((ext_vector_type(4)));

#define LOG2E 1.4426950408889634f
// SCALE = 1/sqrt(32); fold log2(e) so we can use exp2
#define KSCALE (0.17677669529663687f * LOG2E)

#if __has_builtin(__builtin_amdgcn_exp2f)
#define EXP2F(x) __builtin_amdgcn_exp2f(x)
#else
#define EXP2F(x) exp2f(x)
#endif

// DPP row_ror:N (rotate within 16-lane row) — VALU cross-lane, no LDS pipe.
template <int N>
__device__ __forceinline__ int dpp_ror(int v) {
  return __builtin_amdgcn_update_dpp(0, v, 0x120 + N, 0xf, 0xf, true);
}
// 16-lane max-reduce of two independent f16 values packed in h2.
__device__ __forceinline__ h2 rowmax16_h2(h2 v) {
  int t;
  t = dpp_ror<1>(__builtin_bit_cast(int, v));
  v = __builtin_elementwise_max(v, __builtin_bit_cast(h2, t));
  t = dpp_ror<2>(__builtin_bit_cast(int, v));
  v = __builtin_elementwise_max(v, __builtin_bit_cast(h2, t));
  t = dpp_ror<4>(__builtin_bit_cast(int, v));
  v = __builtin_elementwise_max(v, __builtin_bit_cast(h2, t));
  t = dpp_ror<8>(__builtin_bit_cast(int, v));
  v = __builtin_elementwise_max(v, __builtin_bit_cast(h2, t));
  return v;
}
// 16-lane f32 sum-reduce.
__device__ __forceinline__ float rowsum16_f32(float x) {
  int t;
  t = dpp_ror<1>(__builtin_bit_cast(int, x)); x += __builtin_bit_cast(float, t);
  t = dpp_ror<2>(__builtin_bit_cast(int, x)); x += __builtin_bit_cast(float, t);
  t = dpp_ror<4>(__builtin_bit_cast(int, x)); x += __builtin_bit_cast(float, t);
  t = dpp_ror<8>(__builtin_bit_cast(int, x)); x += __builtin_bit_cast(float, t);
  return x;
}

// ---------------------------------------------------------------------------
// prep: [0,1024)   x -> f16 (vector cast)
//       [1024,1072) Wqkv^T via LDS 64x64 tile transpose (4 k-tiles x 12 o-tiles)
//       [1072,1088) Wout^T via LDS tile transpose (16 tiles)
//       [1088,1104) coords layer-1 precompute
// ---------------------------------------------------------------------------
__global__ __launch_bounds__(256) void prep_misc(
    const float* __restrict__ x, const float* __restrict__ Wqkv,
    const float* __restrict__ Wout, const float* __restrict__ coords,
    const float* __restrict__ pw1, const float* __restrict__ pb1,
    const float* __restrict__ sw1, const float* __restrict__ sb1,
    _Float16* __restrict__ xf16, _Float16* __restrict__ WqkvT,
    _Float16* __restrict__ WoutT, _Float16* __restrict__ APre,
    _Float16* __restrict__ BPre)
{
  __shared__ float tile[64][65];
  const int bi = blockIdx.x, tid = threadIdx.x;
  if (bi < 1024) {                       // x cast: 1,048,576 floats
    const int idx = bi * 256 + tid;
    f32x4 v = *reinterpret_cast<const f32x4*>(x + idx * 4);
    half4_t h;
    h[0] = (_Float16)v[0]; h[1] = (_Float16)v[1];
    h[2] = (_Float16)v[2]; h[3] = (_Float16)v[3];
    *reinterpret_cast<half4_t*>(xf16 + idx * 4) = h;
  } else if (bi < 1088) {                // W transposes, 64x64 tiles
    const float* src; _Float16* dst; int t, W;  // W = src row width
    if (bi < 1072) { t = bi - 1024; src = Wqkv; dst = WqkvT; W = 768; }
    else           { t = bi - 1072; src = Wout; dst = WoutT; W = 256; }
    const int nOT = W >> 6;              // o-tiles per k-row
    const int tk = t / nOT, to = t % nOT;
    const int cx = tid & 63, ry = tid >> 6;
#pragma unroll
    for (int rr = 0; rr < 16; ++rr) {
      const int kl = rr * 4 + ry;
      tile[kl][cx] = src[(tk * 64 + kl) * W + to * 64 + cx];
    }
    __syncthreads();
#pragma unroll
    for (int rr = 0; rr < 16; ++rr) {
      const int ol = rr * 4 + ry;
      dst[(to * 64 + ol) * 256 + tk * 64 + cx] = (_Float16)tile[cx][ol];
    }
  } else {                               // coords precompute: 4096 rows
    const int row = (bi - 1088) * 256 + tid;
    const float c0 = coords[row * 3 + 0];
    const float c1 = coords[row * 3 + 1];
    const float c2 = coords[row * 3 + 2];
#pragma unroll
    for (int k = 0; k < 16; ++k) {
      float a = c0 * pw1[k] + c1 * pw1[16 + k] + c2 * pw1[32 + k];
      APre[row * 32 + k] = (_Float16)(a + pb1[k]);
      BPre[row * 32 + k] = (_Float16)a;
      float s  =  c0 * sw1[k] + c1 * sw1[16 + k] + c2 * sw1[32 + k];
      float sb = -c0 * sw1[k] + c1 * sw1[16 + k] + c2 * sw1[32 + k];
      APre[row * 32 + 16 + k] = (_Float16)(s + sb1[k]);
      BPre[row * 32 + 16 + k] = (_Float16)sb;
    }
  }
}

// ---------------------------------------------------------------------------
// qkv_gemm: [4096x768] = xf16[4096x256] @ Wqkv; wave does 16i x 64o (4 tiles,
// A-fragment reused 4x). Scatter epilogue to Qh/Kh [B][H][N][32], Vt [B][H][32][N].
// ---------------------------------------------------------------------------
__global__ __launch_bounds__(256) void qkv_gemm(
    const _Float16* __restrict__ xf16, const _Float16* __restrict__ WqkvT,
    _Float16* __restrict__ Qh, _Float16* __restrict__ Kh,
    _Float16* __restrict__ Vt)
{
  const int wg = blockIdx.x * 4 + (threadIdx.x >> 6);
  const int ti = wg / 12, og = wg % 12;
  const int i0 = ti * 16, o0 = og * 64;
  const int lane = threadIdx.x & 63, q = lane >> 4, c = lane & 15;
  f32x4 acc[4] = {{0,0,0,0},{0,0,0,0},{0,0,0,0},{0,0,0,0}};
  const _Float16* arow = xf16 + (i0 + c) * 256;
  const _Float16* brow = WqkvT + (o0 + c) * 256;
#pragma unroll
  for (int k0 = 0; k0 < 256; k0 += 32) {
    half8_t af = *reinterpret_cast<const half8_t*>(arow + k0 + q * 8);
#pragma unroll
    for (int t = 0; t < 4; ++t) {
      half8_t bf = *reinterpret_cast<const half8_t*>(brow + t * 16 * 256 + k0 + q * 8);
      acc[t] = __builtin_amdgcn_mfma_f32_16x16x32_f16(af, bf, acc[t], 0, 0, 0);
    }
  }
#pragma unroll
  for (int t = 0; t < 4; ++t) {
    const int o = o0 + t * 16 + c;
    const int which = o >> 8, h = (o >> 5) & 7, d = o & 31;
#pragma unroll
    for (int r = 0; r < 4; ++r) {
      const int i = i0 + q * 4 + r;
      const int b = i >> 11, n = i & 2047;
      _Float16 v = (_Float16)acc[t][r];
      if (which == 0)      Qh[((b * 8 + h) * 2048 + n) * 32 + d] = v;
      else if (which == 1) Kh[((b * 8 + h) * 2048 + n) * 32 + d] = v;
      else                 Vt[((b * 8 + h) * 32 + d) * 2048 + n] = v;
    }
  }
}

// ---------------------------------------------------------------------------
// flash: grid = [b:2][chunk:4][itile:128]; block = 512 thr, wave w = head w.
// biasF in f16 (j-stride 20, head-stride 648, dbuf) -> LDS 31 KB -> 4 blk/CU.
// Max-reduce via DPP (no LDS pipe). One barrier per j-tile.
// ---------------------------------------------------------------------------
__global__ __launch_bounds__(512, 8) void flash(
    const _Float16* __restrict__ Qh, const _Float16* __restrict__ Kh,
    const _Float16* __restrict__ Vt, const _Float16* __restrict__ APre,
    const _Float16* __restrict__ BPre, const float* __restrict__ pw2,
    const float* __restrict__ sw2, _Float16* __restrict__ Opart,
    float* __restrict__ Mpart)
{
  __shared__ __align__(16) unsigned char smem[31232];
  _Float16* biasH = reinterpret_cast<_Float16*>(smem);          // [2][8h][32j x 20] f16
  _Float16* pbuf  = reinterpret_cast<_Float16*>(smem + 20992);  // [8w][16i x 40] f16

  const int blk = blockIdx.x;
  const int b     = blk >> 9;
  const int chunk = (blk >> 7) & 3;
  const int i0    = (blk & 127) << 4;
  const int tid = threadIdx.x;
  const int w = tid >> 6, lane = tid & 63;
  const int q = lane >> 4, c = lane & 15;

  // Q fragment (A-operand): row = i0+c, k = d
  half8_t qf = *reinterpret_cast<const half8_t*>(
      Qh + ((b * 8 + w) * 2048 + i0 + c) * 32 + q * 8);
  // APre fragment for bias-MFMA A side (i = c), j-invariant
  half8_t apf = *reinterpret_cast<const half8_t*>(
      APre + (b * 2048 + i0 + c) * 32 + q * 8);

  // stacked W2 B-fragment: B[k][n], k<16 -> pos_w2, k>=16 -> sym_w2; *LOG2E
  half8_t w2f;
#pragma unroll
  for (int jj = 0; jj < 8; ++jj) {
    const int k = q * 8 + jj;
    float val = 0.f;
    if (c < 8) val = (k < 16 ? pw2[k * 8 + c] : sw2[(k - 16) * 8 + c]) * LOG2E;
    w2f[jj] = (_Float16)val;
  }

  float m[4], lp[4];
  f32x4 O0 = {0.f, 0.f, 0.f, 0.f}, O1 = {0.f, 0.f, 0.f, 0.f};
#pragma unroll
  for (int r = 0; r < 4; ++r) { m[r] = -INFINITY; lp[r] = 0.f; }

  const f32x4 z4 = {0.f, 0.f, 0.f, 0.f};
  half8_t hzero8 = {};

  const int jbase = chunk * 512;
  for (int jt = 0; jt < 16; ++jt) {
    const int j0 = jbase + jt * 32;
    _Float16* bW = biasH + (jt & 1) * 5184;

    // ---- bias: reg-resident hidden frag + MFMA, 4 j-columns per wave ----
#pragma unroll
    for (int mt = 0; mt < 4; ++mt) {
      const int jl = w * 4 + mt;
      half8_t bpf = *reinterpret_cast<const half8_t*>(
          BPre + (b * 2048 + j0 + jl) * 32 + q * 8);
      half8_t hv = __builtin_elementwise_max(apf - bpf, hzero8);
      f32x4 bc = __builtin_amdgcn_mfma_f32_16x16x32_f16(hv, w2f, z4, 0, 0, 0);
      if (c < 8) {   // C cols 0..7 = heads; [h][j][i], j-stride 20, h-stride 648
        half4_t b4;
        b4[0] = (_Float16)bc[0]; b4[1] = (_Float16)bc[1];
        b4[2] = (_Float16)bc[2]; b4[3] = (_Float16)bc[3];
        *reinterpret_cast<half4_t*>(bW + c * 648 + jl * 20 + q * 4) = b4;
      }
    }

    // ---- K/V fragments; scores (independent of biasF) ----
    const _Float16* kbase = Kh + ((b * 8 + w) * 2048 + j0) * 32;
    half8_t kf0 = *reinterpret_cast<const half8_t*>(kbase + (2 * c) * 32 + q * 8);
    half8_t kf1 = *reinterpret_cast<const half8_t*>(kbase + (2 * c + 1) * 32 + q * 8);
    const _Float16* vbase = Vt + (b * 8 + w) * 65536 + j0;
    half8_t vf0 = *reinterpret_cast<const half8_t*>(vbase + c * 2048 + q * 8);
    half8_t vf1 = *reinterpret_cast<const half8_t*>(vbase + (16 + c) * 2048 + q * 8);
    f32x4 s0 = __builtin_amdgcn_mfma_f32_16x16x32_f16(qf, kf0, z4, 0, 0, 0);
    f32x4 s1 = __builtin_amdgcn_mfma_f32_16x16x32_f16(qf, kf1, z4, 0, 0, 0);

    __syncthreads();   // biasF[jt&1] ready (sole barrier this iteration)

    const _Float16* bR = biasH + (jt & 1) * 5184 + w * 648;
    half4_t bb0h = *reinterpret_cast<const half4_t*>(bR + (2 * c) * 20 + q * 4);
    half4_t bb1h = *reinterpret_cast<const half4_t*>(bR + (2 * c + 1) * 20 + q * 4);

    // ---- online softmax; rows r in C-layout (row = q*4+r), j = 2c,2c+1 ----
    float sv0[4], sv1[4];
    h2 pk01, pk23;
    {
      float mr[4];
#pragma unroll
      for (int r = 0; r < 4; ++r) {
        sv0[r] = s0[r] * KSCALE + (float)bb0h[r];
        sv1[r] = s1[r] * KSCALE + (float)bb1h[r];
        mr[r] = fmaxf(sv0[r], sv1[r]);
      }
      pk01[0] = (_Float16)mr[0]; pk01[1] = (_Float16)mr[1];
      pk23[0] = (_Float16)mr[2]; pk23[1] = (_Float16)mr[3];
      pk01 = rowmax16_h2(pk01);
      pk23 = rowmax16_h2(pk23);
    }
    float mred[4] = {(float)pk01[0], (float)pk01[1], (float)pk23[0], (float)pk23[1]};
#pragma unroll
    for (int r = 0; r < 4; ++r) {
      const float mnew = fmaxf(m[r], mred[r]);
      const float alpha = EXP2F(m[r] - mnew);
      const float p0 = EXP2F(sv0[r] - mnew);
      const float p1 = EXP2F(sv1[r] - mnew);
      lp[r] = lp[r] * alpha + (p0 + p1);   // lane-local partial; reduce at end
      m[r] = mnew;
      O0[r] *= alpha; O1[r] *= alpha;
      h2 pp; pp[0] = (_Float16)p0; pp[1] = (_Float16)p1;
      *reinterpret_cast<h2*>(pbuf + w * 640 + (q * 4 + r) * 40 + 2 * c) = pp;
    }
    __threadfence_block();   // wave-private pbuf: order write->read, no barrier
    half8_t pf = *reinterpret_cast<const half8_t*>(pbuf + w * 640 + c * 40 + q * 8);
    O0 = __builtin_amdgcn_mfma_f32_16x16x32_f16(pf, vf0, O0, 0, 0, 0);
    O1 = __builtin_amdgcn_mfma_f32_16x16x32_f16(pf, vf1, O1, 0, 0, 0);
  }

  // ---- finalize: reduce l across the 16 lanes of each row, store partials ----
#pragma unroll
  for (int r = 0; r < 4; ++r) {
    const float s = rowsum16_f32(lp[r]);
    const float inv = 1.f / s;
    const int n = i0 + q * 4 + r;
    const long base = (long)(((chunk * 2 + b) * 8 + w) * 2048 + n);
    Opart[base * 32 + c]      = (_Float16)(O0[r] * inv);
    Opart[base * 32 + 16 + c] = (_Float16)(O1[r] * inv);
    if (c == 0) Mpart[base] = m[r] + __log2f(s);
  }
}

// ---------------------------------------------------------------------------
// combine: merge 4 j-chunk partials -> attnF16 [B][N][H*32]; half8 per thread
// ---------------------------------------------------------------------------
__global__ __launch_bounds__(256) void combine(
    const _Float16* __restrict__ Opart, const float* __restrict__ Mpart,
    _Float16* __restrict__ attnF16)
{
  const int idx = blockIdx.x * 256 + threadIdx.x;   // 131072
  const int dg = idx & 3;
  const int h  = (idx >> 2) & 7;
  const int n  = (idx >> 5) & 2047;
  const int b  = idx >> 16;
  float mv[4], M = -INFINITY;
#pragma unroll
  for (int ck = 0; ck < 4; ++ck) {
    mv[ck] = Mpart[((ck * 2 + b) * 8 + h) * 2048 + n];
    M = fmaxf(M, mv[ck]);
  }
  float num[8] = {0,0,0,0,0,0,0,0};
  float den = 0.f;
#pragma unroll
  for (int ck = 0; ck < 4; ++ck) {
    const float wgt = EXP2F(mv[ck] - M);
    half8_t ov = *reinterpret_cast<const half8_t*>(
        Opart + (long)(((ck * 2 + b) * 8 + h) * 2048 + n) * 32 + dg * 8);
#pragma unroll
    for (int e = 0; e < 8; ++e) num[e] += wgt * (float)ov[e];
    den += wgt;
  }
  const float inv = 1.f / den;
  half8_t o;
#pragma unroll
  for (int e = 0; e < 8; ++e) o[e] = (_Float16)(num[e] * inv);
  *reinterpret_cast<half8_t*>(attnF16 + ((b * 2048 + n) * 256 + h * 32 + dg * 8)) = o;
}

// ---------------------------------------------------------------------------
// proj: out = attn @ W_out + b_out; wave does 16i x 64o (4 tiles)
// ---------------------------------------------------------------------------
__global__ __launch_bounds__(256) void proj(
    const _Float16* __restrict__ attnF16, const _Float16* __restrict__ WoutT,
    const float* __restrict__ bout, float* __restrict__ out)
{
  const int i0 = blockIdx.x * 16;
  const int o0 = (threadIdx.x >> 6) * 64;
  const int lane = threadIdx.x & 63, q = lane >> 4, c = lane & 15;
  f32x4 acc[4] = {{0,0,0,0},{0,0,0,0},{0,0,0,0},{0,0,0,0}};
  const _Float16* arow = attnF16 + (i0 + c) * 256;
  const _Float16* brow = WoutT + (o0 + c) * 256;
#pragma unroll
  for (int k0 = 0; k0 < 256; k0 += 32) {
    half8_t af = *reinterpret_cast<const half8_t*>(arow + k0 + q * 8);
#pragma unroll
    for (int t = 0; t < 4; ++t) {
      half8_t bf = *reinterpret_cast<const half8_t*>(brow + t * 16 * 256 + k0 + q * 8);
      acc[t] = __builtin_amdgcn_mfma_f32_16x16x32_f16(af, bf, acc[t], 0, 0, 0);
    }
  }
#pragma unroll
  for (int t = 0; t < 4; ++t) {
    const float bo = bout[o0 + t * 16 + c];
#pragma unroll
    for (int r = 0; r < 4; ++r)
      out[(i0 + q * 4 + r) * 256 + o0 + t * 16 + c] = acc[t][r] + bo;
  }
}

// ---------------------------------------------------------------------------
extern "C" void kernel_launch(void* const* d_in, const int* in_sizes, int n_in,
                              void* d_out, int out_size, void* d_ws, size_t ws_size,
                              hipStream_t stream)
{
  const float* x      = (const float*)d_in[0];
  const float* coords = (const float*)d_in[1];
  const float* Wqkv   = (const float*)d_in[2];
  const float* Wout   = (const float*)d_in[3];
  const float* bout   = (const float*)d_in[4];
  const float* pw1    = (const float*)d_in[5];
  const float* pb1    = (const float*)d_in[6];
  const float* pw2    = (const float*)d_in[7];
  const float* sw1    = (const float*)d_in[9];
  const float* sb1    = (const float*)d_in[10];
  const float* sw2    = (const float*)d_in[11];
  float* out = (float*)d_out;

  char* ws = (char*)d_ws;
  _Float16* Qh      = (_Float16*)(ws + 0);         // 2 MB
  _Float16* Kh      = (_Float16*)(ws + 2097152);   // 2 MB
  _Float16* Vt      = (_Float16*)(ws + 4194304);   // 2 MB
  _Float16* xf16    = (_Float16*)(ws + 6291456);   // 2 MB (dead after qkv_gemm)
  _Float16* attnF16 = (_Float16*)(ws + 6291456);   // overlaid on xf16
  _Float16* WqkvT   = (_Float16*)(ws + 8388608);   // 384 KB
  _Float16* WoutT   = (_Float16*)(ws + 8781824);   // 128 KB
  _Float16* APre    = (_Float16*)(ws + 8912896);   // 256 KB
  _Float16* BPre    = (_Float16*)(ws + 9175040);   // 256 KB
  _Float16* Opart   = (_Float16*)(ws + 9437184);   // 8 MB  [4][2][8][2048][32]
  float*    Mpart   = (float*)   (ws + 17825792);  // 512 KB [4][2][8][2048]

  prep_misc<<<1104, 256, 0, stream>>>(x, Wqkv, Wout, coords, pw1, pb1, sw1, sb1,
                                      xf16, WqkvT, WoutT, APre, BPre);
  qkv_gemm<<<768, 256, 0, stream>>>(xf16, WqkvT, Qh, Kh, Vt);
  flash<<<1024, 512, 0, stream>>>(Qh, Kh, Vt, APre, BPre, pw2, sw2, Opart, Mpart);
  combine<<<512, 256, 0, stream>>>(Opart, Mpart, attnF16);
  proj<<<256, 256, 0, stream>>>(attnF16, WoutT, bout, out);
}